// Round 7
// baseline (38.307 us; speedup 1.0000x reference)
//
#include <hip/hip_runtime.h>

#define BIGF 1.0e6f

static constexpr int C = 3, H = 256, W = 256;
static constexpr int SLICES = 12;
static constexpr int ROWS = SLICES * H;     // 3072
static constexpr int HW = H * W;            // 65536
static constexpr int TOTAL = SLICES * HW;   // 786432
static constexpr int COLS = 16;             // cols per col-block
static constexpr int ROWQ = 64;             // output rows per col-block
static constexpr int PADH = H + 4;          // 260
static constexpr int BPS = 64;              // col blocks per slice

// ---------------------------------------------------------------------------
// Row pass: exact 1D distance along W, one WAVE per row (4 px/lane).
// d[j] = min(j - lastzero<=j, nextzero>=j - j)  ==  reference two-scan.
// u16 storage (0xFFFF = "no zero in row"); decode (float)d*(float)d is
// bit-identical to the f32 path (validated rounds 5-6, absmax 0).
// Block 0 also zeroes the per-slice arrival counters (ws is poisoned 0xAA);
// the kernel boundary makes the zeros visible to col_pass's atomics.
// ---------------------------------------------------------------------------
__global__ void row_pass_kernel(const float* __restrict__ in,
                                unsigned short* __restrict__ g2,
                                unsigned* __restrict__ ctrs) {
    if (blockIdx.x == 0 && threadIdx.x < SLICES * 16) ctrs[threadIdx.x] = 0u;

    int wid = (blockIdx.x * blockDim.x + threadIdx.x) >> 6;   // global wave = row
    int lane = threadIdx.x & 63;
    if (wid >= ROWS) return;

    const float4 v = ((const float4*)(in + (size_t)wid * W))[lane];
    int j0 = lane * 4;
    const int NEG = -(1 << 29), POS = (1 << 29);

    bool z0 = (v.x == 0.0f), z1 = (v.y == 0.0f), z2 = (v.z == 0.0f), z3 = (v.w == 0.0f);
    int lz = NEG;
    if (z0) lz = j0;
    if (z1) lz = j0 + 1;
    if (z2) lz = j0 + 2;
    if (z3) lz = j0 + 3;
    int nz = POS;
    if (z3) nz = j0 + 3;
    if (z2) nz = j0 + 2;
    if (z1) nz = j0 + 1;
    if (z0) nz = j0;

    int plz = lz;
    #pragma unroll
    for (int off = 1; off < 64; off <<= 1) {
        int o = __shfl_up(plz, off);
        if (lane >= off) plz = max(plz, o);
    }
    int ex_lz = __shfl_up(plz, 1);
    if (lane == 0) ex_lz = NEG;

    int pnz = nz;
    #pragma unroll
    for (int off = 1; off < 64; off <<= 1) {
        int o = __shfl_down(pnz, off);
        if (lane + off < 64) pnz = min(pnz, o);
    }
    int ex_nz = __shfl_down(pnz, 1);
    if (lane == 63) ex_nz = POS;

    int lzr = ex_lz;
    int dl0, dl1, dl2, dl3;
    if (z0) lzr = j0;     dl0 = j0 - lzr;
    if (z1) lzr = j0 + 1; dl1 = j0 + 1 - lzr;
    if (z2) lzr = j0 + 2; dl2 = j0 + 2 - lzr;
    if (z3) lzr = j0 + 3; dl3 = j0 + 3 - lzr;

    int nzr = ex_nz;
    int dr0, dr1, dr2, dr3;
    if (z3) nzr = j0 + 3; dr3 = nzr - (j0 + 3);
    if (z2) nzr = j0 + 2; dr2 = nzr - (j0 + 2);
    if (z1) nzr = j0 + 1; dr1 = nzr - (j0 + 1);
    if (z0) nzr = j0;     dr0 = nzr - j0;

    int a0 = min(dl0, dr0), a1 = min(dl1, dr1), a2 = min(dl2, dr2), a3 = min(dl3, dr3);
    ushort4 o;
    o.x = (a0 > 255) ? (unsigned short)0xFFFFu : (unsigned short)a0;
    o.y = (a1 > 255) ? (unsigned short)0xFFFFu : (unsigned short)a1;
    o.z = (a2 > 255) ? (unsigned short)0xFFFFu : (unsigned short)a2;
    o.w = (a3 > 255) ? (unsigned short)0xFFFFu : (unsigned short)a3;
    ((ushort4*)(g2 + (size_t)wid * W))[lane] = o;
}

// ---------------------------------------------------------------------------
// Column pass + fused normalize. Exact windowed min-plus (winning k satisfies
// (i-k)^2 <= g2[i][j]); dt stays in registers. Cross-block slice-max exchange
// is FENCE-FREE: the maxima travel through agent-scope atomics themselves
// (coherence-point ops; round-5 lesson: __threadfence costs ~100ns/block
// serialized -> never use it). Deadlock-safe: capacity >= 5 blocks/CU ->
// 1280 >= 768 all co-resident; guard bound as fail-safe.
// ---------------------------------------------------------------------------
__launch_bounds__(256)
__global__ void col_pass_kernel(const unsigned short* __restrict__ g2,
                                float* __restrict__ out,
                                const float* __restrict__ w,
                                unsigned* __restrict__ bmax_bits,
                                unsigned* __restrict__ ctrs) {
    __shared__ float tileT[COLS][PADH];     // transposed, k contiguous
    __shared__ float wred[4];
    __shared__ float sden;
    const int tid = threadIdx.x;
    const int slice = blockIdx.z;
    const int i0 = blockIdx.y * ROWQ;
    const int j0 = blockIdx.x * COLS;
    const int lblk = blockIdx.y * (W / COLS) + blockIdx.x;   // 0..63 in slice
    const unsigned short* g2s = g2 + (size_t)slice * HW;

    // stage [256 k][16 cols] u16 -> decoded f32, transposed; pad k=256..259
    for (int e = tid; e < H * COLS / 8; e += 256) {
        int k = e >> 1, h = e & 1;          // 8 u16 cols per 16B load
        uint4 u = *(const uint4*)(g2s + (size_t)k * W + j0 + h * 8);
        unsigned uu[4] = {u.x, u.y, u.z, u.w};
        #pragma unroll
        for (int q = 0; q < 4; ++q) {
            unsigned lo = uu[q] & 0xFFFFu, hi = uu[q] >> 16;
            tileT[h * 8 + 2 * q + 0][k] = (lo == 0xFFFFu) ? BIGF * BIGF : (float)lo * (float)lo;
            tileT[h * 8 + 2 * q + 1][k] = (hi == 0xFFFFu) ? BIGF * BIGF : (float)hi * (float)hi;
        }
    }
    if (tid < 64) tileT[tid >> 2][H + (tid & 3)] = 1.0e30f;
    __syncthreads();

    const int jl = tid & (COLS - 1);
    const int ig = tid >> 4;
    const int ibase = i0 + ig * 4;          // 4 output rows per thread

    // wave-uniform exact window from the k=i candidates
    float4 gd = *(const float4*)&tileT[jl][ibase];
    float gmax = fmaxf(fmaxf(gd.x, gd.y), fmaxf(gd.z, gd.w));
    int R = (int)sqrtf(gmax) + 2;
    if (R > 255) R = 255;
    int lo_ = ibase - R, hi_ = ibase + 3 + R;
    #pragma unroll
    for (int off = 1; off < 64; off <<= 1) {
        lo_ = min(lo_, __shfl_xor(lo_, off));
        hi_ = max(hi_, __shfl_xor(hi_, off));
    }
    int kmin = (lo_ < 0 ? 0 : lo_) & ~3;
    int kmax = hi_ > H - 1 ? H - 1 : hi_;

    float m0 = 3.0e38f, m1 = 3.0e38f, m2 = 3.0e38f, m3 = 3.0e38f;
    float d0 = (float)(ibase - kmin);
    float d1 = d0 + 1.0f, d2 = d0 + 2.0f, d3 = d0 + 3.0f;

    const float* rowp = &tileT[jl][0];
    for (int k4 = kmin; k4 <= kmax; k4 += 4) {
        const float4 g = *(const float4*)(rowp + k4);
        {
            float gv = g.x;
            m0 = fminf(m0, fmaf(d0, d0, gv)); d0 -= 1.0f;
            m1 = fminf(m1, fmaf(d1, d1, gv)); d1 -= 1.0f;
            m2 = fminf(m2, fmaf(d2, d2, gv)); d2 -= 1.0f;
            m3 = fminf(m3, fmaf(d3, d3, gv)); d3 -= 1.0f;
        }
        {
            float gv = g.y;
            m0 = fminf(m0, fmaf(d0, d0, gv)); d0 -= 1.0f;
            m1 = fminf(m1, fmaf(d1, d1, gv)); d1 -= 1.0f;
            m2 = fminf(m2, fmaf(d2, d2, gv)); d2 -= 1.0f;
            m3 = fminf(m3, fmaf(d3, d3, gv)); d3 -= 1.0f;
        }
        {
            float gv = g.z;
            m0 = fminf(m0, fmaf(d0, d0, gv)); d0 -= 1.0f;
            m1 = fminf(m1, fmaf(d1, d1, gv)); d1 -= 1.0f;
            m2 = fminf(m2, fmaf(d2, d2, gv)); d2 -= 1.0f;
            m3 = fminf(m3, fmaf(d3, d3, gv)); d3 -= 1.0f;
        }
        {
            float gv = g.w;
            m0 = fminf(m0, fmaf(d0, d0, gv)); d0 -= 1.0f;
            m1 = fminf(m1, fmaf(d1, d1, gv)); d1 -= 1.0f;
            m2 = fminf(m2, fmaf(d2, d2, gv)); d2 -= 1.0f;
            m3 = fminf(m3, fmaf(d3, d3, gv)); d3 -= 1.0f;
        }
    }

    // dt stays in registers
    float v0 = sqrtf(m0), v1 = sqrtf(m1), v2 = sqrtf(m2), v3 = sqrtf(m3);

    // block max -> publish via agent-scope atomics (no fences)
    float lmax = fmaxf(fmaxf(v0, v1), fmaxf(v2, v3));
    #pragma unroll
    for (int off = 32; off; off >>= 1) lmax = fmaxf(lmax, __shfl_down(lmax, off));
    if ((tid & 63) == 0) wred[tid >> 6] = lmax;
    __syncthreads();
    if (tid == 0) {
        float bm = fmaxf(fmaxf(wred[0], wred[1]), fmaxf(wred[2], wred[3]));
        __hip_atomic_store(&bmax_bits[slice * BPS + lblk], __float_as_uint(bm),
                           __ATOMIC_RELAXED, __HIP_MEMORY_SCOPE_AGENT);
        __hip_atomic_fetch_add(&ctrs[slice * 16], 1u,
                               __ATOMIC_RELEASE, __HIP_MEMORY_SCOPE_AGENT);
    }

    // wave 0: wait for all 64 blocks of this slice, reduce their maxima
    if (tid < 64) {
        if (tid == 0) {
            long guard = 0;
            while (__hip_atomic_load(&ctrs[slice * 16], __ATOMIC_ACQUIRE,
                                     __HIP_MEMORY_SCOPE_AGENT) < (unsigned)BPS) {
                __builtin_amdgcn_s_sleep(8);
                if (++guard > (1L << 28)) break;   // fail-safe
            }
        }
        // lanes re-converge here; lane-parallel atomic loads of the 64 slots
        unsigned pb = __hip_atomic_load(&bmax_bits[slice * BPS + tid],
                                        __ATOMIC_RELAXED, __HIP_MEMORY_SCOPE_AGENT);
        float pm = __uint_as_float(pb);
        #pragma unroll
        for (int off = 32; off; off >>= 1) pm = fmaxf(pm, __shfl_xor(pm, off));
        if (tid == 0) sden = pm;
    }
    __syncthreads();

    // normalize in-register, single store (same op order as reference)
    float pmx = sden;
    float den = pmx > 0.0f ? pmx : 1.0f;
    float wc = w[slice % C];
    float* dts = out + (size_t)slice * HW + (size_t)ibase * W + j0 + jl;
    dts[0]     = (v0 / den) * wc;
    dts[W]     = (v1 / den) * wc;
    dts[2 * W] = (v2 / den) * wc;
    dts[3 * W] = (v3 / den) * wc;
}

extern "C" void kernel_launch(void* const* d_in, const int* in_sizes, int n_in,
                              void* d_out, int out_size, void* d_ws, size_t ws_size,
                              hipStream_t stream) {
    const float* in = (const float*)d_in[0];
    const float* w  = (const float*)d_in[1];
    float* out = (float*)d_out;

    unsigned short* g2 = (unsigned short*)d_ws;                       // 1.5 MB
    unsigned* bmax_bits = (unsigned*)((char*)d_ws + (size_t)TOTAL * 2);   // 3 KB
    unsigned* ctrs = (unsigned*)((char*)d_ws + (size_t)TOTAL * 2 + 4096); // 12 x 64B lines

    row_pass_kernel<<<ROWS / 4, 256, 0, stream>>>(in, g2, ctrs);
    col_pass_kernel<<<dim3(W / COLS, H / ROWQ, SLICES), 256, 0, stream>>>(
        g2, out, w, bmax_bits, ctrs);
}

// Round 8
// 20.133 us; speedup vs baseline: 1.9027x; 1.9027x over previous
//
#include <hip/hip_runtime.h>

#define BIGF 1.0e6f

static constexpr int C = 3, H = 256, W = 256;
static constexpr int SLICES = 12;
static constexpr int ROWS = SLICES * H;     // 3072
static constexpr int HW = H * W;            // 65536
static constexpr int TOTAL = SLICES * HW;   // 786432
static constexpr int COLS = 16;             // cols per col-block
static constexpr int ROWQ = 64;             // output rows per col-block
static constexpr int PADH = H + 4;          // 260
static constexpr int BPS = 64;              // col blocks per slice

// ---------------------------------------------------------------------------
// Row pass: exact 1D distance along W, one WAVE per row (4 px/lane).
// d[j] = min(j - lastzero<=j, nextzero>=j - j)  ==  reference two-scan.
// Stored as u16 (0xFFFF sentinel = "no zero in row" = BIG); decode to
// (float)d*(float)d is bit-identical to the f32 path (validated r5/r6).
// ---------------------------------------------------------------------------
__global__ void row_pass_kernel(const float* __restrict__ in,
                                unsigned short* __restrict__ g2) {
    int wid = (blockIdx.x * blockDim.x + threadIdx.x) >> 6;   // global wave = row
    int lane = threadIdx.x & 63;
    if (wid >= ROWS) return;

    const float4 v = ((const float4*)(in + (size_t)wid * W))[lane];
    int j0 = lane * 4;
    const int NEG = -(1 << 29), POS = (1 << 29);

    bool z0 = (v.x == 0.0f), z1 = (v.y == 0.0f), z2 = (v.z == 0.0f), z3 = (v.w == 0.0f);
    int lz = NEG;
    if (z0) lz = j0;
    if (z1) lz = j0 + 1;
    if (z2) lz = j0 + 2;
    if (z3) lz = j0 + 3;
    int nz = POS;
    if (z3) nz = j0 + 3;
    if (z2) nz = j0 + 2;
    if (z1) nz = j0 + 1;
    if (z0) nz = j0;

    int plz = lz;
    #pragma unroll
    for (int off = 1; off < 64; off <<= 1) {
        int o = __shfl_up(plz, off);
        if (lane >= off) plz = max(plz, o);
    }
    int ex_lz = __shfl_up(plz, 1);
    if (lane == 0) ex_lz = NEG;

    int pnz = nz;
    #pragma unroll
    for (int off = 1; off < 64; off <<= 1) {
        int o = __shfl_down(pnz, off);
        if (lane + off < 64) pnz = min(pnz, o);
    }
    int ex_nz = __shfl_down(pnz, 1);
    if (lane == 63) ex_nz = POS;

    int lzr = ex_lz;
    int dl0, dl1, dl2, dl3;
    if (z0) lzr = j0;     dl0 = j0 - lzr;
    if (z1) lzr = j0 + 1; dl1 = j0 + 1 - lzr;
    if (z2) lzr = j0 + 2; dl2 = j0 + 2 - lzr;
    if (z3) lzr = j0 + 3; dl3 = j0 + 3 - lzr;

    int nzr = ex_nz;
    int dr0, dr1, dr2, dr3;
    if (z3) nzr = j0 + 3; dr3 = nzr - (j0 + 3);
    if (z2) nzr = j0 + 2; dr2 = nzr - (j0 + 2);
    if (z1) nzr = j0 + 1; dr1 = nzr - (j0 + 1);
    if (z0) nzr = j0;     dr0 = nzr - j0;

    int a0 = min(dl0, dr0), a1 = min(dl1, dr1), a2 = min(dl2, dr2), a3 = min(dl3, dr3);
    ushort4 o;
    o.x = (a0 > 255) ? (unsigned short)0xFFFFu : (unsigned short)a0;
    o.y = (a1 > 255) ? (unsigned short)0xFFFFu : (unsigned short)a1;
    o.z = (a2 > 255) ? (unsigned short)0xFFFFu : (unsigned short)a2;
    o.w = (a3 > 255) ? (unsigned short)0xFFFFu : (unsigned short)a3;
    ((ushort4*)(g2 + (size_t)wid * W))[lane] = o;
}

// ---------------------------------------------------------------------------
// Column pass: per (slice, 64-row quad, 16-col tile). Exact windowed min-plus
// (winning k satisfies (i-k)^2 <= g2[i][j], the k=i candidate). Per-BLOCK max
// to a dedicated slot -> zero atomics (r3 lesson). NO in-kernel cross-block
// sync of any kind (r5: fences +100us; r7: relaxed agent atomics +18us —
// kernel boundaries are the cheap sync primitive on gfx950).
// ---------------------------------------------------------------------------
__launch_bounds__(256)
__global__ void col_pass_kernel(const unsigned short* __restrict__ g2,
                                float* __restrict__ dt, float* __restrict__ bmax) {
    __shared__ float tileT[COLS][PADH];     // transposed, k contiguous
    __shared__ float wred[4];
    int slice = blockIdx.z;
    int i0 = blockIdx.y * ROWQ;
    int j0 = blockIdx.x * COLS;
    const unsigned short* g2s = g2 + (size_t)slice * HW;

    // stage [256 k][16 cols] u16 -> decoded f32, transposed; pad k=256..259
    for (int e = threadIdx.x; e < H * COLS / 8; e += 256) {
        int k = e >> 1, h = e & 1;          // 8 u16 cols per 16B load
        uint4 u = *(const uint4*)(g2s + (size_t)k * W + j0 + h * 8);
        unsigned uu[4] = {u.x, u.y, u.z, u.w};
        #pragma unroll
        for (int q = 0; q < 4; ++q) {
            unsigned lo = uu[q] & 0xFFFFu, hi = uu[q] >> 16;
            tileT[h * 8 + 2 * q + 0][k] = (lo == 0xFFFFu) ? BIGF * BIGF : (float)lo * (float)lo;
            tileT[h * 8 + 2 * q + 1][k] = (hi == 0xFFFFu) ? BIGF * BIGF : (float)hi * (float)hi;
        }
    }
    if (threadIdx.x < 64)
        tileT[threadIdx.x >> 2][H + (threadIdx.x & 3)] = 1.0e30f;
    __syncthreads();

    int jl = threadIdx.x & (COLS - 1);
    int ig = threadIdx.x >> 4;
    int ibase = i0 + ig * 4;            // 4 output rows per thread

    // wave-uniform exact window from the k=i candidates
    float4 gd = *(const float4*)&tileT[jl][ibase];
    float gmax = fmaxf(fmaxf(gd.x, gd.y), fmaxf(gd.z, gd.w));
    int R = (int)sqrtf(gmax) + 2;
    if (R > 255) R = 255;
    int lo = ibase - R, hi = ibase + 3 + R;
    #pragma unroll
    for (int off = 1; off < 64; off <<= 1) {
        lo = min(lo, __shfl_xor(lo, off));
        hi = max(hi, __shfl_xor(hi, off));
    }
    int kmin = (lo < 0 ? 0 : lo) & ~3;
    int kmax = hi > H - 1 ? H - 1 : hi;

    float m0 = 3.0e38f, m1 = 3.0e38f, m2 = 3.0e38f, m3 = 3.0e38f;
    float d0 = (float)(ibase - kmin);
    float d1 = d0 + 1.0f, d2 = d0 + 2.0f, d3 = d0 + 3.0f;

    const float* rowp = &tileT[jl][0];
    for (int k4 = kmin; k4 <= kmax; k4 += 4) {
        const float4 g = *(const float4*)(rowp + k4);
        {
            float gv = g.x;
            m0 = fminf(m0, fmaf(d0, d0, gv)); d0 -= 1.0f;
            m1 = fminf(m1, fmaf(d1, d1, gv)); d1 -= 1.0f;
            m2 = fminf(m2, fmaf(d2, d2, gv)); d2 -= 1.0f;
            m3 = fminf(m3, fmaf(d3, d3, gv)); d3 -= 1.0f;
        }
        {
            float gv = g.y;
            m0 = fminf(m0, fmaf(d0, d0, gv)); d0 -= 1.0f;
            m1 = fminf(m1, fmaf(d1, d1, gv)); d1 -= 1.0f;
            m2 = fminf(m2, fmaf(d2, d2, gv)); d2 -= 1.0f;
            m3 = fminf(m3, fmaf(d3, d3, gv)); d3 -= 1.0f;
        }
        {
            float gv = g.z;
            m0 = fminf(m0, fmaf(d0, d0, gv)); d0 -= 1.0f;
            m1 = fminf(m1, fmaf(d1, d1, gv)); d1 -= 1.0f;
            m2 = fminf(m2, fmaf(d2, d2, gv)); d2 -= 1.0f;
            m3 = fminf(m3, fmaf(d3, d3, gv)); d3 -= 1.0f;
        }
        {
            float gv = g.w;
            m0 = fminf(m0, fmaf(d0, d0, gv)); d0 -= 1.0f;
            m1 = fminf(m1, fmaf(d1, d1, gv)); d1 -= 1.0f;
            m2 = fminf(m2, fmaf(d2, d2, gv)); d2 -= 1.0f;
            m3 = fminf(m3, fmaf(d3, d3, gv)); d3 -= 1.0f;
        }
    }

    float* dts = dt + (size_t)slice * HW + (size_t)ibase * W + j0 + jl;
    float v0 = sqrtf(m0), v1 = sqrtf(m1), v2 = sqrtf(m2), v3 = sqrtf(m3);
    dts[0] = v0; dts[W] = v1; dts[2 * W] = v2; dts[3 * W] = v3;

    // block-level max, ONE plain store per block (no atomics)
    float lmax = fmaxf(fmaxf(v0, v1), fmaxf(v2, v3));
    #pragma unroll
    for (int off = 32; off; off >>= 1) lmax = fmaxf(lmax, __shfl_down(lmax, off));
    if ((threadIdx.x & 63) == 0) wred[threadIdx.x >> 6] = lmax;
    __syncthreads();
    if (threadIdx.x == 0) {
        float bm = fmaxf(fmaxf(wred[0], wred[1]), fmaxf(wred[2], wred[3]));
        bmax[slice * BPS + blockIdx.y * (W / COLS) + blockIdx.x] = bm;
    }
}

// out = (dt / max) * w[c]; slice max rebuilt from 64 per-block maxima
// via a 64-lane load + shfl reduction (exact, order-free).
__global__ void norm_kernel(float* __restrict__ out, const float* __restrict__ bmax,
                            const float* __restrict__ w) {
    int idx = blockIdx.x * blockDim.x + threadIdx.x;   // float4 index
    if (idx >= TOTAL / 4) return;
    int slice = idx >> 14;              // uniform within a block
    int c = slice % C;

    int lane = threadIdx.x & 63;
    float pm = bmax[slice * BPS + lane];
    #pragma unroll
    for (int off = 32; off; off >>= 1) pm = fmaxf(pm, __shfl_xor(pm, off));

    float den = pm > 0.0f ? pm : 1.0f;
    float wc = w[c];
    float4 v = ((float4*)out)[idx];
    v.x = (v.x / den) * wc;
    v.y = (v.y / den) * wc;
    v.z = (v.z / den) * wc;
    v.w = (v.w / den) * wc;
    ((float4*)out)[idx] = v;
}

extern "C" void kernel_launch(void* const* d_in, const int* in_sizes, int n_in,
                              void* d_out, int out_size, void* d_ws, size_t ws_size,
                              hipStream_t stream) {
    const float* in = (const float*)d_in[0];
    const float* w  = (const float*)d_in[1];
    float* out = (float*)d_out;

    unsigned short* g2 = (unsigned short*)d_ws;                 // 1.5 MB
    float* bmax = (float*)((char*)d_ws + (size_t)TOTAL * 2);    // 3 KB

    row_pass_kernel<<<ROWS / 4, 256, 0, stream>>>(in, g2);
    col_pass_kernel<<<dim3(W / COLS, H / ROWQ, SLICES), 256, 0, stream>>>(g2, out, bmax);
    norm_kernel<<<(TOTAL / 4 + 255) / 256, 256, 0, stream>>>(out, bmax, w);
}

// Round 9
// 19.953 us; speedup vs baseline: 1.9198x; 1.0090x over previous
//
#include <hip/hip_runtime.h>

#define BIGF 1.0e6f

static constexpr int C = 3, H = 256, W = 256;
static constexpr int SLICES = 12;
static constexpr int ROWS = SLICES * H;     // 3072
static constexpr int HW = H * W;            // 65536
static constexpr int TOTAL = SLICES * HW;   // 786432
static constexpr int COLS = 16;             // cols per col-block
static constexpr int ROWQ = 64;             // output rows per col-block
static constexpr int PADH = H + 4;          // 260
static constexpr int BPS = 64;              // col blocks per slice

// ---------------------------------------------------------------------------
// Row pass: exact 1D distance along W, one WAVE per row (4 px/lane).
// d[j] = min(j - lastzero<=j, nextzero>=j - j)  ==  reference two-scan.
// Stored as u16 d (0xFFFF sentinel = "no zero in row" = BIG); decode
// (float)d*(float)d is bit-identical to the f32 path (validated r5-r8).
// ---------------------------------------------------------------------------
__global__ void row_pass_kernel(const float* __restrict__ in,
                                unsigned short* __restrict__ g2) {
    int wid = (blockIdx.x * blockDim.x + threadIdx.x) >> 6;   // global wave = row
    int lane = threadIdx.x & 63;
    if (wid >= ROWS) return;

    const float4 v = ((const float4*)(in + (size_t)wid * W))[lane];
    int j0 = lane * 4;
    const int NEG = -(1 << 29), POS = (1 << 29);

    bool z0 = (v.x == 0.0f), z1 = (v.y == 0.0f), z2 = (v.z == 0.0f), z3 = (v.w == 0.0f);
    int lz = NEG;
    if (z0) lz = j0;
    if (z1) lz = j0 + 1;
    if (z2) lz = j0 + 2;
    if (z3) lz = j0 + 3;
    int nz = POS;
    if (z3) nz = j0 + 3;
    if (z2) nz = j0 + 2;
    if (z1) nz = j0 + 1;
    if (z0) nz = j0;

    int plz = lz;
    #pragma unroll
    for (int off = 1; off < 64; off <<= 1) {
        int o = __shfl_up(plz, off);
        if (lane >= off) plz = max(plz, o);
    }
    int ex_lz = __shfl_up(plz, 1);
    if (lane == 0) ex_lz = NEG;

    int pnz = nz;
    #pragma unroll
    for (int off = 1; off < 64; off <<= 1) {
        int o = __shfl_down(pnz, off);
        if (lane + off < 64) pnz = min(pnz, o);
    }
    int ex_nz = __shfl_down(pnz, 1);
    if (lane == 63) ex_nz = POS;

    int lzr = ex_lz;
    int dl0, dl1, dl2, dl3;
    if (z0) lzr = j0;     dl0 = j0 - lzr;
    if (z1) lzr = j0 + 1; dl1 = j0 + 1 - lzr;
    if (z2) lzr = j0 + 2; dl2 = j0 + 2 - lzr;
    if (z3) lzr = j0 + 3; dl3 = j0 + 3 - lzr;

    int nzr = ex_nz;
    int dr0, dr1, dr2, dr3;
    if (z3) nzr = j0 + 3; dr3 = nzr - (j0 + 3);
    if (z2) nzr = j0 + 2; dr2 = nzr - (j0 + 2);
    if (z1) nzr = j0 + 1; dr1 = nzr - (j0 + 1);
    if (z0) nzr = j0;     dr0 = nzr - j0;

    int a0 = min(dl0, dr0), a1 = min(dl1, dr1), a2 = min(dl2, dr2), a3 = min(dl3, dr3);
    ushort4 o;
    o.x = (a0 > 255) ? (unsigned short)0xFFFFu : (unsigned short)a0;
    o.y = (a1 > 255) ? (unsigned short)0xFFFFu : (unsigned short)a1;
    o.z = (a2 > 255) ? (unsigned short)0xFFFFu : (unsigned short)a2;
    o.w = (a3 > 255) ? (unsigned short)0xFFFFu : (unsigned short)a3;
    ((ushort4*)(g2 + (size_t)wid * W))[lane] = o;
}

// ---------------------------------------------------------------------------
// Column pass: per (slice, 64-row quad, 16-col tile). Exact windowed min-plus:
// winner k satisfies (i-k)^2 <= d_i^2  <=>  |i-k| <= d_i (all exact ints),
// so radius comes straight from the u16 candidates (no sqrt). Staging is
// restricted to the block-wide window [kminb, kmaxb+3] (~half of 256 rows).
// fminf over a superset window with identical candidate values is order-free
// -> bitwise-identical result. Per-BLOCK max to a dedicated slot (r3 lesson:
// no atomics); no cross-block sync (r5/r7 lesson: boundaries are cheaper).
// ---------------------------------------------------------------------------
__launch_bounds__(256)
__global__ void col_pass_kernel(const unsigned short* __restrict__ g2,
                                float* __restrict__ dt, float* __restrict__ bmax) {
    __shared__ float tileT[COLS][PADH];     // transposed, k contiguous
    __shared__ float wred[4];
    __shared__ int slo[4], shi[4];
    const int tid = threadIdx.x;
    const int slice = blockIdx.z;
    const int i0 = blockIdx.y * ROWQ;
    const int j0 = blockIdx.x * COLS;
    const unsigned short* g2s = g2 + (size_t)slice * HW;

    const int jl = tid & (COLS - 1);
    const int ig = tid >> 4;
    const int ibase = i0 + ig * 4;          // 4 output rows per thread

    // exact per-thread radius from the k=i candidates (direct global reads)
    int c0 = g2s[(size_t)(ibase + 0) * W + j0 + jl];
    int c1 = g2s[(size_t)(ibase + 1) * W + j0 + jl];
    int c2 = g2s[(size_t)(ibase + 2) * W + j0 + jl];
    int c3 = g2s[(size_t)(ibase + 3) * W + j0 + jl];
    int cm = max(max(c0, c1), max(c2, c3));
    int R = (cm > 254 ? 254 : cm) + 1;      // |i-k| <= d_i, +1 slack

    int lo_ = ibase - R, hi_ = ibase + 3 + R;
    #pragma unroll
    for (int off = 1; off < 64; off <<= 1) {
        lo_ = min(lo_, __shfl_xor(lo_, off));
        hi_ = max(hi_, __shfl_xor(hi_, off));
    }
    int kmin = (lo_ < 0 ? 0 : lo_) & ~3;
    int kmax = hi_ > H - 1 ? H - 1 : hi_;

    // block-wide staging range
    if ((tid & 63) == 0) { slo[tid >> 6] = kmin; shi[tid >> 6] = kmax; }
    __syncthreads();
    int kminb = min(min(slo[0], slo[1]), min(slo[2], slo[3]));  // >=0, 4-aligned
    int kmaxb = max(max(shi[0], shi[1]), max(shi[2], shi[3]));  // <= H-1

    // stage rows [kminb, kmaxb+3] u16 -> decoded f32, transposed; k>=H -> 1e30
    int nrows = kmaxb + 4 - kminb;
    for (int e = tid; e < nrows * 2; e += 256) {
        int k = kminb + (e >> 1), h = e & 1;    // 8 u16 cols per 16B load
        if (k < H) {
            uint4 u = *(const uint4*)(g2s + (size_t)k * W + j0 + h * 8);
            unsigned uu[4] = {u.x, u.y, u.z, u.w};
            #pragma unroll
            for (int q = 0; q < 4; ++q) {
                unsigned lo = uu[q] & 0xFFFFu, hi = uu[q] >> 16;
                tileT[h * 8 + 2 * q + 0][k] = (lo == 0xFFFFu) ? BIGF * BIGF : (float)lo * (float)lo;
                tileT[h * 8 + 2 * q + 1][k] = (hi == 0xFFFFu) ? BIGF * BIGF : (float)hi * (float)hi;
            }
        } else {
            #pragma unroll
            for (int q = 0; q < 8; ++q) tileT[h * 8 + q][k] = 1.0e30f;
        }
    }
    __syncthreads();

    float m0 = 3.0e38f, m1 = 3.0e38f, m2 = 3.0e38f, m3 = 3.0e38f;
    float d0 = (float)(ibase - kmin);
    float d1 = d0 + 1.0f, d2 = d0 + 2.0f, d3 = d0 + 3.0f;

    const float* rowp = &tileT[jl][0];
    for (int k4 = kmin; k4 <= kmax; k4 += 4) {
        const float4 g = *(const float4*)(rowp + k4);
        {
            float gv = g.x;
            m0 = fminf(m0, fmaf(d0, d0, gv)); d0 -= 1.0f;
            m1 = fminf(m1, fmaf(d1, d1, gv)); d1 -= 1.0f;
            m2 = fminf(m2, fmaf(d2, d2, gv)); d2 -= 1.0f;
            m3 = fminf(m3, fmaf(d3, d3, gv)); d3 -= 1.0f;
        }
        {
            float gv = g.y;
            m0 = fminf(m0, fmaf(d0, d0, gv)); d0 -= 1.0f;
            m1 = fminf(m1, fmaf(d1, d1, gv)); d1 -= 1.0f;
            m2 = fminf(m2, fmaf(d2, d2, gv)); d2 -= 1.0f;
            m3 = fminf(m3, fmaf(d3, d3, gv)); d3 -= 1.0f;
        }
        {
            float gv = g.z;
            m0 = fminf(m0, fmaf(d0, d0, gv)); d0 -= 1.0f;
            m1 = fminf(m1, fmaf(d1, d1, gv)); d1 -= 1.0f;
            m2 = fminf(m2, fmaf(d2, d2, gv)); d2 -= 1.0f;
            m3 = fminf(m3, fmaf(d3, d3, gv)); d3 -= 1.0f;
        }
        {
            float gv = g.w;
            m0 = fminf(m0, fmaf(d0, d0, gv)); d0 -= 1.0f;
            m1 = fminf(m1, fmaf(d1, d1, gv)); d1 -= 1.0f;
            m2 = fminf(m2, fmaf(d2, d2, gv)); d2 -= 1.0f;
            m3 = fminf(m3, fmaf(d3, d3, gv)); d3 -= 1.0f;
        }
    }

    float* dts = dt + (size_t)slice * HW + (size_t)ibase * W + j0 + jl;
    float v0 = sqrtf(m0), v1 = sqrtf(m1), v2 = sqrtf(m2), v3 = sqrtf(m3);
    dts[0] = v0; dts[W] = v1; dts[2 * W] = v2; dts[3 * W] = v3;

    // block-level max, ONE plain store per block (no atomics)
    float lmax = fmaxf(fmaxf(v0, v1), fmaxf(v2, v3));
    #pragma unroll
    for (int off = 32; off; off >>= 1) lmax = fmaxf(lmax, __shfl_down(lmax, off));
    if ((tid & 63) == 0) wred[tid >> 6] = lmax;
    __syncthreads();
    if (tid == 0) {
        float bm = fmaxf(fmaxf(wred[0], wred[1]), fmaxf(wred[2], wred[3]));
        bmax[slice * BPS + blockIdx.y * (W / COLS) + blockIdx.x] = bm;
    }
}

// out = (dt / max) * w[c]; 2 float4 per thread (32B), slice max rebuilt from
// the 64 per-block maxima via lane-parallel load + shfl (exact, order-free).
__global__ void norm_kernel(float* __restrict__ out, const float* __restrict__ bmax,
                            const float* __restrict__ w) {
    int t = blockIdx.x * blockDim.x + threadIdx.x;
    if (t >= TOTAL / 8) return;
    int idx = t * 2;                    // float4 index; 8 floats never straddle a slice
    int slice = idx >> 14;
    int c = slice % C;

    int lane = threadIdx.x & 63;
    float pm = bmax[slice * BPS + lane];
    #pragma unroll
    for (int off = 32; off; off >>= 1) pm = fmaxf(pm, __shfl_xor(pm, off));

    float den = pm > 0.0f ? pm : 1.0f;
    float wc = w[c];
    float4 a = ((float4*)out)[idx];
    float4 b = ((float4*)out)[idx + 1];
    a.x = (a.x / den) * wc; a.y = (a.y / den) * wc;
    a.z = (a.z / den) * wc; a.w = (a.w / den) * wc;
    b.x = (b.x / den) * wc; b.y = (b.y / den) * wc;
    b.z = (b.z / den) * wc; b.w = (b.w / den) * wc;
    ((float4*)out)[idx] = a;
    ((float4*)out)[idx + 1] = b;
}

extern "C" void kernel_launch(void* const* d_in, const int* in_sizes, int n_in,
                              void* d_out, int out_size, void* d_ws, size_t ws_size,
                              hipStream_t stream) {
    const float* in = (const float*)d_in[0];
    const float* w  = (const float*)d_in[1];
    float* out = (float*)d_out;

    unsigned short* g2 = (unsigned short*)d_ws;                 // 1.5 MB
    float* bmax = (float*)((char*)d_ws + (size_t)TOTAL * 2);    // 3 KB

    row_pass_kernel<<<ROWS / 4, 256, 0, stream>>>(in, g2);
    col_pass_kernel<<<dim3(W / COLS, H / ROWQ, SLICES), 256, 0, stream>>>(g2, out, bmax);
    norm_kernel<<<(TOTAL / 8 + 255) / 256, 256, 0, stream>>>(out, bmax, w);
}